// Round 1
// baseline (2331.715 us; speedup 1.0000x reference)
//
#include <hip/hip_runtime.h>

#define D 128

// ---------------------------------------------------------------------------
// Scatter: agg[dst[e]] += x[src[e]] * (1/attr[e])
// One edge per 32 lanes (quarter-wave); each lane handles a float4 (16B).
// 512B contiguous per edge -> coalesced gather; atomics are native f32 adds.
// ---------------------------------------------------------------------------
__global__ __launch_bounds__(256) void scatter_kernel(
    const float* __restrict__ x, const int* __restrict__ src,
    const int* __restrict__ dst, const float* __restrict__ attr,
    float* __restrict__ agg, int E)
{
    long long t = (long long)blockIdx.x * blockDim.x + threadIdx.x;
    int e = (int)(t >> 5);
    if (e >= E) return;
    int c = ((int)t & 31) << 2;

    int s = src[e];
    int d = dst[e];
    float inv = 1.0f / attr[e];

    const float4 v = *(const float4*)(x + (long long)s * D + c);
    float* out = agg + (long long)d * D + c;
    unsafeAtomicAdd(out + 0, v.x * inv);
    unsafeAtomicAdd(out + 1, v.y * inv);
    unsafeAtomicAdd(out + 2, v.z * inv);
    unsafeAtomicAdd(out + 3, v.w * inv);
}

// ---------------------------------------------------------------------------
// Y = relu(A @ W^T + b), A:[N,128], W:[128,128] (row j = output col j)
// Block = 256 threads, 32 rows per block.
// LDS: W transposed, row stride 132 floats (528B, 16B-aligned -> float4 reads,
// conflict-free). A tile stride 128 (scalar reads, 2-way aliasing = free).
// Each thread: 4 rows x 4 cols -> 16 FMA per (1 ds_read_b128 + 4 ds_read_b32).
// ---------------------------------------------------------------------------
__global__ __launch_bounds__(256) void gemm_relu_kernel(
    const float* __restrict__ A, const float* __restrict__ W,
    const float* __restrict__ b, float* __restrict__ Y, int N)
{
    __shared__ float Wt[128 * 132];   // Wt[k*132 + j] = W[j*128 + k]
    __shared__ float As[32 * 128];

    const int t = threadIdx.x;

    // Stage W transposed (coalesced float4 global loads, scalar LDS writes).
    const float4* W4 = (const float4*)W;
    #pragma unroll
    for (int q = 0; q < 16; ++q) {
        int f4 = q * 256 + t;
        int flat = f4 << 2;          // element index j*128+k
        int j = flat >> 7;
        int k = flat & 127;
        float4 w = W4[f4];
        Wt[(k + 0) * 132 + j] = w.x;
        Wt[(k + 1) * 132 + j] = w.y;
        Wt[(k + 2) * 132 + j] = w.z;
        Wt[(k + 3) * 132 + j] = w.w;
    }

    // Stage the 32-row A tile (float4 in, float4 layout, stride 128).
    const int base = blockIdx.x * 32;
    const float4* A4 = (const float4*)(A + (long long)base * D);
    float4* As4 = (float4*)As;
    #pragma unroll
    for (int q = 0; q < 4; ++q)
        As4[q * 256 + t] = A4[q * 256 + t];

    __syncthreads();

    const int cg  = t & 31;          // column group
    const int col = cg << 2;         // 4 output cols
    const int rg  = t >> 5;          // row group (0..7), 4 rows each

    const float4 bb = *(const float4*)(b + col);
    float4 acc[4];
    #pragma unroll
    for (int i = 0; i < 4; ++i) acc[i] = bb;

    #pragma unroll 4
    for (int k = 0; k < 128; ++k) {
        float4 w = *(const float4*)&Wt[k * 132 + col];
        #pragma unroll
        for (int i = 0; i < 4; ++i) {
            float a = As[(rg * 4 + i) * 128 + k];
            acc[i].x += a * w.x;
            acc[i].y += a * w.y;
            acc[i].z += a * w.z;
            acc[i].w += a * w.w;
        }
    }

    #pragma unroll
    for (int i = 0; i < 4; ++i) {
        float4 r = acc[i];
        r.x = r.x > 0.0f ? r.x : 0.0f;
        r.y = r.y > 0.0f ? r.y : 0.0f;
        r.z = r.z > 0.0f ? r.z : 0.0f;
        r.w = r.w > 0.0f ? r.w : 0.0f;
        int row = base + rg * 4 + i;
        *(float4*)(Y + (long long)row * D + col) = r;
    }
}

// ---------------------------------------------------------------------------
// x1 = relu(scatter(x) @ W1^T + b1); out = relu(scatter(x1) @ W2^T + b2)
// ws layout: bufA (N*D f32) | bufB (N*D f32)
// ---------------------------------------------------------------------------
extern "C" void kernel_launch(void* const* d_in, const int* in_sizes, int n_in,
                              void* d_out, int out_size, void* d_ws, size_t ws_size,
                              hipStream_t stream)
{
    const float* x    = (const float*)d_in[0];
    const int*   eidx = (const int*)d_in[1];   // [2, E] flat, int32
    const float* attr = (const float*)d_in[2];
    const float* W1   = (const float*)d_in[3];
    const float* b1   = (const float*)d_in[4];
    const float* W2   = (const float*)d_in[5];
    const float* b2   = (const float*)d_in[6];

    const int N = in_sizes[0] / D;
    const int E = in_sizes[2];
    const int* src = eidx;
    const int* dst = eidx + E;

    const size_t nbytes = (size_t)N * D * sizeof(float);
    float* bufA = (float*)d_ws;
    float* bufB = (float*)((char*)d_ws + nbytes);

    const int sblocks = (E * 32 + 255) / 256;   // one edge per 32 lanes
    const int gblocks = (N + 31) / 32;

    // Layer 1
    hipMemsetAsync(bufA, 0, nbytes, stream);
    scatter_kernel<<<sblocks, 256, 0, stream>>>(x, src, dst, attr, bufA, E);
    gemm_relu_kernel<<<gblocks, 256, 0, stream>>>(bufA, W1, b1, bufB, N);

    // Layer 2
    hipMemsetAsync(bufA, 0, nbytes, stream);
    scatter_kernel<<<sblocks, 256, 0, stream>>>(bufB, src, dst, attr, bufA, E);
    gemm_relu_kernel<<<gblocks, 256, 0, stream>>>(bufA, W2, b2, (float*)d_out, N);
}

// Round 2
// 375.748 us; speedup vs baseline: 6.2055x; 6.2055x over previous
//
#include <hip/hip_runtime.h>

#define D 128

// ---------------------------------------------------------------------------
// CSR build: histogram of dst -> exclusive scan -> bucket fill.
// ---------------------------------------------------------------------------
__global__ __launch_bounds__(256) void hist_kernel(
    const int* __restrict__ dst, int* __restrict__ counts, int E)
{
    int e = blockIdx.x * 256 + threadIdx.x;
    if (e < E) atomicAdd(&counts[dst[e]], 1);
}

// Exclusive scan of 256-element tiles; per-block total to bsum.
__global__ __launch_bounds__(256) void scan_block_kernel(
    const int* __restrict__ in, int* __restrict__ out,
    int* __restrict__ bsum, int n)
{
    int gid = blockIdx.x * 256 + threadIdx.x;
    int c = (gid < n) ? in[gid] : 0;
    int lane = threadIdx.x & 63, w = threadIdx.x >> 6;
    int v = c;
    #pragma unroll
    for (int o = 1; o < 64; o <<= 1) {
        int t = __shfl_up(v, o);
        if (lane >= o) v += t;
    }
    __shared__ int wsum[4], woff[4];
    if (lane == 63) wsum[w] = v;
    __syncthreads();
    if (threadIdx.x == 0) {
        int s = 0;
        #pragma unroll
        for (int i = 0; i < 4; ++i) { woff[i] = s; s += wsum[i]; }
        bsum[blockIdx.x] = s;
    }
    __syncthreads();
    if (gid < n) out[gid] = v - c + woff[w];
}

__global__ __launch_bounds__(256) void scan_add_kernel(
    int* __restrict__ offs, const int* __restrict__ bsumoff, int n, int total)
{
    int gid = blockIdx.x * 256 + threadIdx.x;
    if (gid < n) offs[gid] += bsumoff[blockIdx.x];
    if (gid == 0) offs[n] = total;   // sentinel: offs[N] = E
}

// Fill buckets: combo[pos] = { src[e], 1/attr[e] } (8B, one load in gather).
__global__ __launch_bounds__(256) void fill_kernel(
    const int* __restrict__ src, const int* __restrict__ dst,
    const float* __restrict__ attr, const int* __restrict__ offs,
    int* __restrict__ cursor, int2* __restrict__ combo, int E)
{
    int e = blockIdx.x * 256 + threadIdx.x;
    if (e >= E) return;
    int d = dst[e];
    int pos = offs[d] + atomicAdd(&cursor[d], 1);
    int2 c;
    c.x = src[e];
    c.y = __float_as_int(1.0f / attr[e]);
    combo[pos] = c;
}

// ---------------------------------------------------------------------------
// Gather: agg[n] = sum over in-edges of x[src] * inv_attr. One wave per node,
// each lane holds float2 (64*8B = 512B/row, fully coalesced). No atomics.
// Deg-0 nodes write zeros (matches segment_sum).
// ---------------------------------------------------------------------------
__global__ __launch_bounds__(256) void gather_kernel(
    const float* __restrict__ x, const int2* __restrict__ combo,
    const int* __restrict__ offs, float* __restrict__ agg, int N)
{
    int node = blockIdx.x * 4 + (threadIdx.x >> 6);
    int lane = threadIdx.x & 63;
    if (node >= N) return;
    int i0 = offs[node], i1 = offs[node + 1];
    float2 acc = {0.0f, 0.0f};
    for (int i = i0; i < i1; ++i) {
        int2 se = combo[i];                       // uniform across the wave
        float inv = __int_as_float(se.y);
        const float2 v = *(const float2*)(x + (long long)se.x * D + lane * 2);
        acc.x += v.x * inv;
        acc.y += v.y * inv;
    }
    *(float2*)(agg + (long long)node * D + lane * 2) = acc;
}

// ---------------------------------------------------------------------------
// Y = relu(A @ W^T + b), A:[N,128], W:[128,128]. Block = 256 thr, 32 rows.
// Wt stride 132 -> aligned float4 LDS reads, conflict-free.
// ---------------------------------------------------------------------------
__global__ __launch_bounds__(256) void gemm_relu_kernel(
    const float* __restrict__ A, const float* __restrict__ W,
    const float* __restrict__ b, float* __restrict__ Y, int N)
{
    __shared__ float Wt[128 * 132];   // Wt[k*132 + j] = W[j*128 + k]
    __shared__ float As[32 * 128];

    const int t = threadIdx.x;

    const float4* W4 = (const float4*)W;
    #pragma unroll
    for (int q = 0; q < 16; ++q) {
        int f4 = q * 256 + t;
        int flat = f4 << 2;
        int j = flat >> 7;
        int k = flat & 127;
        float4 w = W4[f4];
        Wt[(k + 0) * 132 + j] = w.x;
        Wt[(k + 1) * 132 + j] = w.y;
        Wt[(k + 2) * 132 + j] = w.z;
        Wt[(k + 3) * 132 + j] = w.w;
    }

    const int base = blockIdx.x * 32;
    const float4* A4 = (const float4*)(A + (long long)base * D);
    float4* As4 = (float4*)As;
    #pragma unroll
    for (int q = 0; q < 4; ++q)
        As4[q * 256 + t] = A4[q * 256 + t];

    __syncthreads();

    const int cg  = t & 31;
    const int col = cg << 2;
    const int rg  = t >> 5;

    const float4 bb = *(const float4*)(b + col);
    float4 acc[4];
    #pragma unroll
    for (int i = 0; i < 4; ++i) acc[i] = bb;

    #pragma unroll 4
    for (int k = 0; k < 128; ++k) {
        float4 w = *(const float4*)&Wt[k * 132 + col];
        #pragma unroll
        for (int i = 0; i < 4; ++i) {
            float a = As[(rg * 4 + i) * 128 + k];
            acc[i].x += a * w.x;
            acc[i].y += a * w.y;
            acc[i].z += a * w.z;
            acc[i].w += a * w.w;
        }
    }

    #pragma unroll
    for (int i = 0; i < 4; ++i) {
        float4 r = acc[i];
        r.x = r.x > 0.0f ? r.x : 0.0f;
        r.y = r.y > 0.0f ? r.y : 0.0f;
        r.z = r.z > 0.0f ? r.z : 0.0f;
        r.w = r.w > 0.0f ? r.w : 0.0f;
        int row = base + rg * 4 + i;
        *(float4*)(Y + (long long)row * D + col) = r;
    }
}

// ---------------------------------------------------------------------------
// x1 = relu(gather(x) @ W1^T + b1)  -> d_out (scratch)
// out = relu(gather(x1) @ W2^T + b2) -> d_out
// ---------------------------------------------------------------------------
extern "C" void kernel_launch(void* const* d_in, const int* in_sizes, int n_in,
                              void* d_out, int out_size, void* d_ws, size_t ws_size,
                              hipStream_t stream)
{
    const float* x    = (const float*)d_in[0];
    const int*   eidx = (const int*)d_in[1];
    const float* attr = (const float*)d_in[2];
    const float* W1   = (const float*)d_in[3];
    const float* b1   = (const float*)d_in[4];
    const float* W2   = (const float*)d_in[5];
    const float* b2   = (const float*)d_in[6];

    const int N = in_sizes[0] / D;        // 40000
    const int E = in_sizes[2];            // 640000
    const int* src = eidx;
    const int* dst = eidx + E;

    // ws layout (16B-aligned regions)
    char* p = (char*)d_ws;
    float* bufA    = (float*)p;            p += (size_t)N * D * sizeof(float);
    int2*  combo   = (int2*)p;             p += (size_t)E * sizeof(int2);
    int*   offs    = (int*)p;              p += ((size_t)(N + 1) * 4 + 15) & ~15ULL;
    int*   bsum    = (int*)p;              p += 256 * 4;
    int*   bsumoff = (int*)p;              p += 256 * 4;
    int*   dummy   = (int*)p;              p += 64;
    int*   counts  = (int*)p;              p += (size_t)N * 4;
    int*   cursor  = (int*)p;              /* p += N*4 */

    const int eblocks = (E + 255) / 256;          // 2500
    const int nblocks = (N + 255) / 256;          // 157
    const int gatherb = (N + 3) / 4;              // 10000
    const int gemmb   = (N + 31) / 32;            // 1250

    // CSR build (once per call; counts & cursor are adjacent -> one memset)
    hipMemsetAsync(counts, 0, (size_t)2 * N * 4, stream);
    hist_kernel<<<eblocks, 256, 0, stream>>>(dst, counts, E);
    scan_block_kernel<<<nblocks, 256, 0, stream>>>(counts, offs, bsum, N);
    scan_block_kernel<<<1, 256, 0, stream>>>(bsum, bsumoff, dummy, nblocks);
    scan_add_kernel<<<nblocks, 256, 0, stream>>>(offs, bsumoff, N, E);
    fill_kernel<<<eblocks, 256, 0, stream>>>(src, dst, attr, offs, cursor, combo, E);

    // Layer 1
    gather_kernel<<<gatherb, 256, 0, stream>>>(x, combo, offs, bufA, N);
    gemm_relu_kernel<<<gemmb, 256, 0, stream>>>(bufA, W1, b1, (float*)d_out, N);

    // Layer 2
    gather_kernel<<<gatherb, 256, 0, stream>>>((const float*)d_out, combo, offs, bufA, N);
    gemm_relu_kernel<<<gemmb, 256, 0, stream>>>(bufA, W2, b2, (float*)d_out, N);
}

// Round 3
// 279.906 us; speedup vs baseline: 8.3304x; 1.3424x over previous
//
#include <hip/hip_runtime.h>

#define D 128

// ---------------------------------------------------------------------------
// CSR build: histogram of dst -> exclusive scan -> bucket fill.
// ---------------------------------------------------------------------------
__global__ __launch_bounds__(256) void hist_kernel(
    const int* __restrict__ dst, int* __restrict__ counts, int E)
{
    int e = blockIdx.x * 256 + threadIdx.x;
    if (e < E) atomicAdd(&counts[dst[e]], 1);
}

__global__ __launch_bounds__(256) void scan_block_kernel(
    const int* __restrict__ in, int* __restrict__ out,
    int* __restrict__ bsum, int n)
{
    int gid = blockIdx.x * 256 + threadIdx.x;
    int c = (gid < n) ? in[gid] : 0;
    int lane = threadIdx.x & 63, w = threadIdx.x >> 6;
    int v = c;
    #pragma unroll
    for (int o = 1; o < 64; o <<= 1) {
        int t = __shfl_up(v, o);
        if (lane >= o) v += t;
    }
    __shared__ int wsum[4], woff[4];
    if (lane == 63) wsum[w] = v;
    __syncthreads();
    if (threadIdx.x == 0) {
        int s = 0;
        #pragma unroll
        for (int i = 0; i < 4; ++i) { woff[i] = s; s += wsum[i]; }
        bsum[blockIdx.x] = s;
    }
    __syncthreads();
    if (gid < n) out[gid] = v - c + woff[w];
}

__global__ __launch_bounds__(256) void scan_add_kernel(
    int* __restrict__ offs, const int* __restrict__ bsumoff, int n, int total)
{
    int gid = blockIdx.x * 256 + threadIdx.x;
    if (gid < n) offs[gid] += bsumoff[blockIdx.x];
    if (gid == 0) offs[n] = total;
}

__global__ __launch_bounds__(256) void fill_kernel(
    const int* __restrict__ src, const int* __restrict__ dst,
    const float* __restrict__ attr, const int* __restrict__ offs,
    int* __restrict__ cursor, int2* __restrict__ combo, int E)
{
    int e = blockIdx.x * 256 + threadIdx.x;
    if (e >= E) return;
    int d = dst[e];
    int pos = offs[d] + atomicAdd(&cursor[d], 1);
    int2 c;
    c.x = src[e];
    c.y = __float_as_int(1.0f / attr[e]);
    combo[pos] = c;
}

// ---------------------------------------------------------------------------
// Gather: one 64-lane wave per node. Half-wave 0 = edge i, half-wave 1 =
// edge i+1; each lane float4 (32 lanes x 16B = one 512B row). Unroll x2 ->
// 4 edges / 4 independent load chains in flight. __shfl_xor(32) to combine
// halves; lanes 0-31 store the row. No atomics; deg-0 nodes write zeros.
// ---------------------------------------------------------------------------
__global__ __launch_bounds__(256) void gather_kernel(
    const float* __restrict__ x, const int2* __restrict__ combo,
    const int* __restrict__ offs, float* __restrict__ agg, int N)
{
    const int node = (blockIdx.x * 256 + threadIdx.x) >> 6;
    if (node >= N) return;
    const int lane = threadIdx.x & 63;
    const int half = lane >> 5;          // 0 or 1
    const int l32  = lane & 31;
    const int cofs = l32 * 4;

    const int i0 = offs[node], i1 = offs[node + 1];
    float4 acc0 = {0.f, 0.f, 0.f, 0.f};
    float4 acc1 = {0.f, 0.f, 0.f, 0.f};

    int i = i0;
    for (; i + 3 < i1; i += 4) {
        int2 ca = combo[i + half];           // broadcast per half-wave
        int2 cb = combo[i + 2 + half];
        const float4 va = *(const float4*)(x + (long long)ca.x * D + cofs);
        const float4 vb = *(const float4*)(x + (long long)cb.x * D + cofs);
        float fa = __int_as_float(ca.y);
        float fb = __int_as_float(cb.y);
        acc0.x += va.x * fa; acc0.y += va.y * fa;
        acc0.z += va.z * fa; acc0.w += va.w * fa;
        acc1.x += vb.x * fb; acc1.y += vb.y * fb;
        acc1.z += vb.z * fb; acc1.w += vb.w * fb;
    }
    if (i + 1 < i1) {                        // pair tail
        int2 ca = combo[i + half];
        const float4 va = *(const float4*)(x + (long long)ca.x * D + cofs);
        float fa = __int_as_float(ca.y);
        acc0.x += va.x * fa; acc0.y += va.y * fa;
        acc0.z += va.z * fa; acc0.w += va.w * fa;
        i += 2;
    }
    if (i < i1 && half == 0) {               // single tail (lower half only)
        int2 ca = combo[i];
        const float4 va = *(const float4*)(x + (long long)ca.x * D + cofs);
        float fa = __int_as_float(ca.y);
        acc1.x += va.x * fa; acc1.y += va.y * fa;
        acc1.z += va.z * fa; acc1.w += va.w * fa;
    }

    float4 s;
    s.x = acc0.x + acc1.x; s.y = acc0.y + acc1.y;
    s.z = acc0.z + acc1.z; s.w = acc0.w + acc1.w;
    s.x += __shfl_xor(s.x, 32);
    s.y += __shfl_xor(s.y, 32);
    s.z += __shfl_xor(s.z, 32);
    s.w += __shfl_xor(s.w, 32);
    if (half == 0)
        *(float4*)(agg + (long long)node * D + cofs) = s;
}

// ---------------------------------------------------------------------------
// Y = relu(A @ W^T + b). Block = 256 thr, 32 rows. K-tiled: Wt chunk 32x132
// (16.9 KB) + As 32x128 (16.4 KB) = 33.3 KB LDS -> 4 blocks/CU, 16 waves/CU.
// Inner loop: all-float4 LDS reads; W reads conflict-free (stride 132),
// A reads half-wave-uniform broadcasts. Thread = 4 rows x 4 cols.
// ---------------------------------------------------------------------------
__global__ __launch_bounds__(256) void gemm_relu_kernel(
    const float* __restrict__ A, const float* __restrict__ W,
    const float* __restrict__ b, float* __restrict__ Y, int N)
{
    __shared__ float Wt[32 * 132];   // Wt[k'*132 + j] = W[j*128 + c*32 + k']
    __shared__ float As[32 * 128];

    const int t = threadIdx.x;
    const int base = blockIdx.x * 32;

    // Stage the 32-row A tile (coalesced float4).
    const float4* A4 = (const float4*)(A + (long long)base * D);
    float4* As4 = (float4*)As;
    #pragma unroll
    for (int q = 0; q < 4; ++q)
        As4[q * 256 + t] = A4[q * 256 + t];

    const int cg  = t & 31;
    const int col = cg << 2;
    const int rg  = t >> 5;

    const float4 bb = *(const float4*)(b + col);
    float4 acc[4];
    #pragma unroll
    for (int i = 0; i < 4; ++i) acc[i] = bb;

    const float4* W4 = (const float4*)W;

    #pragma unroll 1
    for (int c = 0; c < 4; ++c) {
        __syncthreads();   // Wt reuse fence (also covers As on c=0)
        // Stage Wt chunk c: thread loads 4 float4 of W, scatters transposed.
        #pragma unroll
        for (int q = 0; q < 4; ++q) {
            int f4 = q * 256 + t;
            int j  = f4 >> 3;        // W row (= output col)
            int fc = f4 & 7;         // float4 within the 32-wide K chunk
            float4 w = W4[j * 32 + c * 8 + fc];
            int k = fc << 2;
            Wt[(k + 0) * 132 + j] = w.x;
            Wt[(k + 1) * 132 + j] = w.y;
            Wt[(k + 2) * 132 + j] = w.z;
            Wt[(k + 3) * 132 + j] = w.w;
        }
        __syncthreads();

        const int kb0 = c * 32;
        #pragma unroll 2
        for (int kb = 0; kb < 32; kb += 4) {
            float4 w0 = *(const float4*)&Wt[(kb + 0) * 132 + col];
            float4 w1 = *(const float4*)&Wt[(kb + 1) * 132 + col];
            float4 w2 = *(const float4*)&Wt[(kb + 2) * 132 + col];
            float4 w3 = *(const float4*)&Wt[(kb + 3) * 132 + col];
            #pragma unroll
            for (int i = 0; i < 4; ++i) {
                float4 a = *(const float4*)&As[(rg * 4 + i) * 128 + kb0 + kb];
                acc[i].x = fmaf(a.x, w0.x, fmaf(a.y, w1.x, fmaf(a.z, w2.x, fmaf(a.w, w3.x, acc[i].x))));
                acc[i].y = fmaf(a.x, w0.y, fmaf(a.y, w1.y, fmaf(a.z, w2.y, fmaf(a.w, w3.y, acc[i].y))));
                acc[i].z = fmaf(a.x, w0.z, fmaf(a.y, w1.z, fmaf(a.z, w2.z, fmaf(a.w, w3.z, acc[i].z))));
                acc[i].w = fmaf(a.x, w0.w, fmaf(a.y, w1.w, fmaf(a.z, w2.w, fmaf(a.w, w3.w, acc[i].w))));
            }
        }
    }

    #pragma unroll
    for (int i = 0; i < 4; ++i) {
        float4 r = acc[i];
        r.x = r.x > 0.0f ? r.x : 0.0f;
        r.y = r.y > 0.0f ? r.y : 0.0f;
        r.z = r.z > 0.0f ? r.z : 0.0f;
        r.w = r.w > 0.0f ? r.w : 0.0f;
        int row = base + rg * 4 + i;
        *(float4*)(Y + (long long)row * D + col) = r;
    }
}

// ---------------------------------------------------------------------------
// x1 = relu(gather(x) @ W1^T + b1)  -> d_out (scratch)
// out = relu(gather(x1) @ W2^T + b2) -> d_out
// ---------------------------------------------------------------------------
extern "C" void kernel_launch(void* const* d_in, const int* in_sizes, int n_in,
                              void* d_out, int out_size, void* d_ws, size_t ws_size,
                              hipStream_t stream)
{
    const float* x    = (const float*)d_in[0];
    const int*   eidx = (const int*)d_in[1];
    const float* attr = (const float*)d_in[2];
    const float* W1   = (const float*)d_in[3];
    const float* b1   = (const float*)d_in[4];
    const float* W2   = (const float*)d_in[5];
    const float* b2   = (const float*)d_in[6];

    const int N = in_sizes[0] / D;        // 40000
    const int E = in_sizes[2];            // 640000
    const int* src = eidx;
    const int* dst = eidx + E;

    // ws layout (16B-aligned regions)
    char* p = (char*)d_ws;
    float* bufA    = (float*)p;            p += (size_t)N * D * sizeof(float);
    int2*  combo   = (int2*)p;             p += (size_t)E * sizeof(int2);
    int*   offs    = (int*)p;              p += ((size_t)(N + 1) * 4 + 15) & ~15ULL;
    int*   bsum    = (int*)p;              p += 256 * 4;
    int*   bsumoff = (int*)p;              p += 256 * 4;
    int*   dummy   = (int*)p;              p += 64;
    int*   counts  = (int*)p;              p += (size_t)N * 4;
    int*   cursor  = (int*)p;              /* p += N*4 */

    const int eblocks = (E + 255) / 256;          // 2500
    const int nblocks = (N + 255) / 256;          // 157
    const int gatherb = (N + 3) / 4;              // 10000 (4 waves/block)
    const int gemmb   = (N + 31) / 32;            // 1250

    // CSR build (counts & cursor adjacent -> one memset)
    hipMemsetAsync(counts, 0, (size_t)2 * N * 4, stream);
    hist_kernel<<<eblocks, 256, 0, stream>>>(dst, counts, E);
    scan_block_kernel<<<nblocks, 256, 0, stream>>>(counts, offs, bsum, N);
    scan_block_kernel<<<1, 256, 0, stream>>>(bsum, bsumoff, dummy, nblocks);
    scan_add_kernel<<<nblocks, 256, 0, stream>>>(offs, bsumoff, N, E);
    fill_kernel<<<eblocks, 256, 0, stream>>>(src, dst, attr, offs, cursor, combo, E);

    // Layer 1
    gather_kernel<<<gatherb, 256, 0, stream>>>(x, combo, offs, bufA, N);
    gemm_relu_kernel<<<gemmb, 256, 0, stream>>>(bufA, W1, b1, (float*)d_out, N);

    // Layer 2
    gather_kernel<<<gatherb, 256, 0, stream>>>((const float*)d_out, combo, offs, bufA, N);
    gemm_relu_kernel<<<gemmb, 256, 0, stream>>>(bufA, W2, b2, (float*)d_out, N);
}